// Round 1
// baseline (996.901 us; speedup 1.0000x reference)
//
#include <hip/hip_runtime.h>
#include <math.h>

// Problem constants (match reference)
static constexpr int ND  = 150000;   // total nodes
static constexpr int NUU = 100000;   // num users
static constexpr int BB  = 16384;    // batch
static constexpr int EE  = 2000000;  // edges (before self loops)
static constexpr int ETOT = EE + ND; // edges incl self loops

// ---------------- wave helpers ----------------
__device__ __forceinline__ float wsum64(float v){
#pragma unroll
  for (int d = 32; d > 0; d >>= 1) v += __shfl_xor(v, d, 64);
  return v;
}
__device__ __forceinline__ float wmax64(float v){
#pragma unroll
  for (int d = 32; d > 0; d >>= 1) v = fmaxf(v, __shfl_xor(v, d, 64));
  return v;
}

// ---------------- input scatter ----------------
// x[uid][0:64] = user_emb_w[uid]   (upper half stays zero from memset)
__global__ __launch_bounds__(256) void k_users(const int* __restrict__ uids,
    const float* __restrict__ uemb, float* __restrict__ x){
  int t = blockIdx.x * 256 + threadIdx.x;
  if (t >= BB * 64) return;
  int b = t >> 6, c = t & 63;
  int uid = uids[b];
  x[(size_t)uid * 128 + c] = uemb[(size_t)uid * 64 + c];
}

// items: x[NU+iid][0:64] = item_emb[iid]; x[NU+iid][64:128] = content[b]@cp_w + cp_b
// one wave -> 4 rows; lane = output col
__global__ __launch_bounds__(256) void k_items(const float* __restrict__ content,
    const float* __restrict__ cpw, const float* __restrict__ cpb,
    const float* __restrict__ iemb, const int* __restrict__ iids,
    float* __restrict__ x){
  int c  = threadIdx.x & 63;
  int rr = threadIdx.x >> 6;
  int r0 = blockIdx.x * 16 + rr * 4;
  float acc[4] = {0.f, 0.f, 0.f, 0.f};
  for (int k = 0; k < 256; k++) {
    float wv = cpw[k * 64 + c];           // coalesced, L2-resident (64KB)
#pragma unroll
    for (int i = 0; i < 4; i++)
      acc[i] = fmaf(content[(size_t)(r0 + i) * 256 + k], wv, acc[i]); // wave-uniform scalar load
  }
#pragma unroll
  for (int i = 0; i < 4; i++) {
    int r = r0 + i;
    if (r >= BB) continue;
    int iid = iids[r];
    size_t node = (size_t)(NUU + iid);
    x[node * 128 + 64 + c] = acc[i] + cpb[c];
    x[node * 128 + c]      = iemb[(size_t)iid * 64 + c];
  }
}

// ---------------- CSR build (by dst) ----------------
__global__ __launch_bounds__(256) void k_count(const int* __restrict__ ei,
    int* __restrict__ deg){
  int t = blockIdx.x * 256 + threadIdx.x;
  if (t >= ETOT) return;
  int dst = (t < EE) ? ei[EE + t] : (t - EE);
  atomicAdd(&deg[dst], 1);
}

__global__ __launch_bounds__(1024) void k_scan(const int* __restrict__ deg,
    int* __restrict__ offs, int* __restrict__ cursor, int n){
  __shared__ int wsums[16];
  __shared__ int carry_s;
  int tid = threadIdx.x;
  int lane = tid & 63, w = tid >> 6;
  if (tid == 0) carry_s = 0;
  __syncthreads();
  int nchunks = (n + 4095) / 4096;
  for (int c = 0; c < nchunks; c++) {
    int idx = c * 4096 + tid * 4;
    int4 v = make_int4(0, 0, 0, 0);
    if (idx + 3 < n) v = *(const int4*)(deg + idx);
    else {
      if (idx     < n) v.x = deg[idx];
      if (idx + 1 < n) v.y = deg[idx + 1];
      if (idx + 2 < n) v.z = deg[idx + 2];
      if (idx + 3 < n) v.w = deg[idx + 3];
    }
    int s = v.x + v.y + v.z + v.w;
    int x = s;
#pragma unroll
    for (int d = 1; d < 64; d <<= 1) { int t2 = __shfl_up(x, d, 64); if (lane >= d) x += t2; }
    if (lane == 63) wsums[w] = x;
    __syncthreads();
    if (w == 0) {
      int t3 = (lane < 16) ? wsums[lane] : 0;
#pragma unroll
      for (int d = 1; d < 16; d <<= 1) { int t2 = __shfl_up(t3, d, 64); if (lane >= d) t3 += t2; }
      if (lane < 16) wsums[lane] = t3;
    }
    __syncthreads();
    int chunk_total = wsums[15];
    int base = carry_s + ((w > 0) ? wsums[w - 1] : 0) + (x - s);
    int4 o; o.x = base; o.y = base + v.x; o.z = o.y + v.y; o.w = o.z + v.z;
    if (idx + 3 < n) { *(int4*)(offs + idx) = o; *(int4*)(cursor + idx) = o; }
    else {
      if (idx     < n) { offs[idx]     = o.x; cursor[idx]     = o.x; }
      if (idx + 1 < n) { offs[idx + 1] = o.y; cursor[idx + 1] = o.y; }
      if (idx + 2 < n) { offs[idx + 2] = o.z; cursor[idx + 2] = o.z; }
      if (idx + 3 < n) { offs[idx + 3] = o.w; cursor[idx + 3] = o.w; }
    }
    __syncthreads();
    if (tid == 0) carry_s += chunk_total;
    __syncthreads();
  }
  if (threadIdx.x == 0) offs[n] = carry_s;
}

__global__ __launch_bounds__(256) void k_fill(const int* __restrict__ ei,
    int* __restrict__ cursor, int* __restrict__ csr){
  int t = blockIdx.x * 256 + threadIdx.x;
  if (t >= ETOT) return;
  int src, dst;
  if (t < EE) { src = ei[t]; dst = ei[EE + t]; }
  else        { src = dst = t - EE; }
  int pos = atomicAdd(&cursor[dst], 1);
  csr[pos] = src;
}

// ---------------- fp32 GEMM: C[M,Ncols] = A[M,128] @ W[128,Ncols] ----------------
// 64x64 tile, BK=64 two-stage, 4x4 per-thread register tile. LDS stride 68 -> <=2-way conflicts.
__global__ __launch_bounds__(256) void k_gemm(const float* __restrict__ A,
    const float* __restrict__ W, float* __restrict__ C, int M, int Ncols){
  __shared__ __align__(16) float As[64 * 68];
  __shared__ __align__(16) float Ws[64 * 68];
  int tid = threadIdx.x;
  int m_base = blockIdx.x * 64;
  int n_base = blockIdx.y * 64;
  int tm = (tid >> 4) * 4;
  int tn = (tid & 15) * 4;
  float acc[4][4];
#pragma unroll
  for (int i = 0; i < 4; i++)
#pragma unroll
    for (int j = 0; j < 4; j++) acc[i][j] = 0.f;

  int lm = tid >> 2;   // 0..63
  int lq = tid & 3;    // 0..3
  for (int ks = 0; ks < 128; ks += 64) {
#pragma unroll
    for (int p = 0; p < 4; p++) {
      int k4 = lq + p * 4;
      float4 v = make_float4(0.f, 0.f, 0.f, 0.f);
      int gm = m_base + lm;
      if (gm < M) v = *(const float4*)(A + (size_t)gm * 128 + ks + k4 * 4);
      *(float4*)(As + lm * 68 + k4 * 4) = v;
    }
#pragma unroll
    for (int p = 0; p < 4; p++) {
      int n4 = lq + p * 4;
      float4 v = *(const float4*)(W + (size_t)(ks + lm) * Ncols + n_base + n4 * 4);
      *(float4*)(Ws + lm * 68 + n4 * 4) = v;
    }
    __syncthreads();
#pragma unroll
    for (int kk = 0; kk < 64; kk += 4) {
      float a_arr[4][4], w_arr[4][4];
#pragma unroll
      for (int i = 0; i < 4; i++) {
        float4 a = *(const float4*)(As + (tm + i) * 68 + kk);
        a_arr[i][0] = a.x; a_arr[i][1] = a.y; a_arr[i][2] = a.z; a_arr[i][3] = a.w;
      }
#pragma unroll
      for (int q = 0; q < 4; q++) {
        float4 wv = *(const float4*)(Ws + (kk + q) * 68 + tn);
        w_arr[q][0] = wv.x; w_arr[q][1] = wv.y; w_arr[q][2] = wv.z; w_arr[q][3] = wv.w;
      }
#pragma unroll
      for (int q = 0; q < 4; q++)
#pragma unroll
        for (int i = 0; i < 4; i++)
#pragma unroll
          for (int j = 0; j < 4; j++)
            acc[i][j] = fmaf(a_arr[i][q], w_arr[q][j], acc[i][j]);
    }
    __syncthreads();
  }
#pragma unroll
  for (int i = 0; i < 4; i++) {
    int gm = m_base + tm + i;
    if (gm < M) {
      float4 o = make_float4(acc[i][0], acc[i][1], acc[i][2], acc[i][3]);
      *(float4*)(C + (size_t)gm * Ncols + n_base + tn) = o;
    }
  }
}

// ---------------- per-node attention scores ----------------
template<int H>
__global__ __launch_bounds__(256) void k_scores(const float* __restrict__ xw,
    const float* __restrict__ asrc, const float* __restrict__ adst,
    float* __restrict__ als, float* __restrict__ ald, int n){
  int gw = (blockIdx.x * 256 + threadIdx.x) >> 6;
  int lane = threadIdx.x & 63;
  if (gw >= n) return;
  const int S = H * 64;
#pragma unroll
  for (int h = 0; h < H; h++) {
    float v  = xw[(size_t)gw * S + h * 64 + lane];
    float ps = wsum64(v * asrc[h * 64 + lane]);
    float pd = wsum64(v * adst[h * 64 + lane]);
    if (lane == 0) { als[(size_t)gw * H + h] = ps; ald[(size_t)gw * H + h] = pd; }
  }
}

// ---------------- GAT aggregation: one wave per dst node ----------------
template<int H, bool ELU>
__global__ __launch_bounds__(256) void k_agg(const float* __restrict__ xw,
    const float* __restrict__ als, const float* __restrict__ ald,
    const int* __restrict__ offs, const int* __restrict__ csr,
    const float* __restrict__ bias, float* __restrict__ out, int n){
  int gw = (blockIdx.x * 256 + threadIdx.x) >> 6;
  int lane = threadIdx.x & 63;
  if (gw >= n) return;
  int dst = gw;
  int e0 = offs[dst], e1 = offs[dst + 1];
  const int S = H * 64;
  float aldd[H], m_run[H], den[H], acc[H];
#pragma unroll
  for (int h = 0; h < H; h++) {
    aldd[h] = ald[(size_t)dst * H + h];
    m_run[h] = -INFINITY; den[h] = 0.f; acc[h] = 0.f;
  }
  for (int base = e0; base < e1; base += 64) {
    int e = base + lane;
    bool valid = (e < e1);
    int src = valid ? csr[e] : 0;
    int cnt = (e1 - base < 64) ? (e1 - base) : 64;
    float p[H];
#pragma unroll
    for (int h = 0; h < H; h++) {
      float s;
      if (valid) {
        float v = als[(size_t)src * H + h] + aldd[h];
        s = (v > 0.f) ? v : 0.2f * v;              // leaky_relu(.,0.2)
      } else s = -INFINITY;
      float mc = wmax64(s);
      float m_new = fmaxf(m_run[h], mc);
      float scale = expf(m_run[h] - m_new);        // exp(-inf)=0 on first chunk
      float pe = valid ? expf(s - m_new) : 0.f;
      den[h] = den[h] * scale + wsum64(pe);
      acc[h] *= scale;
      m_run[h] = m_new;
      p[h] = pe;
    }
    for (int j = 0; j < cnt; j++) {
      int sj = __shfl(src, j, 64);
      const float* row = xw + (size_t)sj * S + lane;
#pragma unroll
      for (int h = 0; h < H; h++) {
        float pj = __shfl(p[h], j, 64);
        acc[h] = fmaf(pj, row[h * 64], acc[h]);    // coalesced 256B gather
      }
    }
  }
#pragma unroll
  for (int h = 0; h < H; h++) {
    float v = acc[h] / (den[h] + 1e-16f) + bias[h * 64 + lane];
    if (ELU) v = (v > 0.f) ? v : expm1f(v);        // elu, alpha=1
    out[(size_t)dst * S + h * 64 + lane] = v;
  }
}

// ---------------- prediction head: one wave per batch row ----------------
__global__ __launch_bounds__(256) void k_head(const float* __restrict__ uemb,
    const int* __restrict__ uids, const int* __restrict__ iids,
    const float* __restrict__ x2, const float* __restrict__ pw1,
    const float* __restrict__ pb1, const float* __restrict__ pw2,
    const float* __restrict__ pb2, float* __restrict__ out, int B){
  __shared__ __align__(16) float pw1_s[192 * 64];  // 48KB
  __shared__ float comb_s[4][192];
  for (int i = threadIdx.x; i < 192 * 64 / 4; i += 256)
    ((float4*)pw1_s)[i] = ((const float4*)pw1)[i];
  int w = threadIdx.x >> 6, lane = threadIdx.x & 63;
  int b = blockIdx.x * 4 + w;
  if (b < B) {
    int uid = uids[b], iid = iids[b];
    comb_s[w][lane]       = uemb[(size_t)uid * 64 + lane];
    comb_s[w][64 + lane]  = x2[(size_t)(NUU + iid) * 64 + lane];
    comb_s[w][128 + lane] = x2[(size_t)uid * 64 + lane];
  }
  __syncthreads();
  if (b >= B) return;
  float acc = pb1[lane];
#pragma unroll 8
  for (int j = 0; j < 192; j++)
    acc = fmaf(comb_s[w][j], pw1_s[j * 64 + lane], acc);
  acc = fmaxf(acc, 0.f);
  float prod = wsum64(acc * pw2[lane]);
  if (lane == 0) out[b] = prod + pb2[0];
}

// ---------------- launcher ----------------
extern "C" void kernel_launch(void* const* d_in, const int* in_sizes, int n_in,
                              void* d_out, int out_size, void* d_ws, size_t ws_size,
                              hipStream_t stream) {
  (void)in_sizes; (void)n_in; (void)out_size; (void)ws_size;
  const int*   user_ids = (const int*)  d_in[0];
  const int*   item_ids = (const int*)  d_in[1];
  const float* content  = (const float*)d_in[2];
  const int*   edge_idx = (const int*)  d_in[3];
  const float* uemb     = (const float*)d_in[4];
  const float* iemb     = (const float*)d_in[5];
  const float* cp_w     = (const float*)d_in[6];
  const float* cp_b     = (const float*)d_in[7];
  const float* w1       = (const float*)d_in[8];
  const float* asrc1    = (const float*)d_in[9];
  const float* adst1    = (const float*)d_in[10];
  const float* b1       = (const float*)d_in[11];
  const float* w2       = (const float*)d_in[12];
  const float* asrc2    = (const float*)d_in[13];
  const float* adst2    = (const float*)d_in[14];
  const float* b2       = (const float*)d_in[15];
  const float* pw1      = (const float*)d_in[16];
  const float* pb1      = (const float*)d_in[17];
  const float* pw2      = (const float*)d_in[18];
  const float* pb2      = (const float*)d_in[19];
  float* out = (float*)d_out;

  // workspace layout (~167 MB)
  float* x   = (float*)d_ws;                  // [ND,128] node features; reused as h1 (layer-1 out)
  float* xw  = x  + (size_t)ND * 128;         // [ND,128] xw1; layer2: xw2=[0:ND*64), out2=[ND*64:ND*128)
  float* als = xw + (size_t)ND * 128;         // [ND,2]
  float* ald = als + (size_t)ND * 2;          // [ND,2]
  int* deg    = (int*)(ald + (size_t)ND * 2); // [ND]
  int* offs   = deg + ND;                     // [ND+4] (padded so cursor is 16B aligned)
  int* cursor = offs + ND + 4;                // [ND]
  int* csr    = cursor + ND;                  // [ETOT]
  float* out2 = xw + (size_t)ND * 64;

  hipMemsetAsync(x, 0, (size_t)ND * 128 * sizeof(float), stream);
  hipMemsetAsync(deg, 0, ND * sizeof(int), stream);

  k_users<<<(BB * 64 + 255) / 256, 256, 0, stream>>>(user_ids, uemb, x);
  k_items<<<BB / 16, 256, 0, stream>>>(content, cp_w, cp_b, iemb, item_ids, x);

  k_count<<<(ETOT + 255) / 256, 256, 0, stream>>>(edge_idx, deg);
  k_scan<<<1, 1024, 0, stream>>>(deg, offs, cursor, ND);
  k_fill<<<(ETOT + 255) / 256, 256, 0, stream>>>(edge_idx, cursor, csr);

  // ----- GAT layer 1 (H=2) -----
  k_gemm<<<dim3((ND + 63) / 64, 2), 256, 0, stream>>>(x, w1, xw, ND, 128);
  k_scores<2><<<(ND * 64 + 255) / 256, 256, 0, stream>>>(xw, asrc1, adst1, als, ald, ND);
  k_agg<2, true><<<(ND * 64 + 255) / 256, 256, 0, stream>>>(xw, als, ald, offs, csr, b1, x, ND);

  // ----- GAT layer 2 (H=1) -----
  k_gemm<<<dim3((ND + 63) / 64, 1), 256, 0, stream>>>(x, w2, xw, ND, 64);
  k_scores<1><<<(ND * 64 + 255) / 256, 256, 0, stream>>>(xw, asrc2, adst2, als, ald, ND);
  k_agg<1, false><<<(ND * 64 + 255) / 256, 256, 0, stream>>>(xw, als, ald, offs, csr, b2, out2, ND);

  // ----- head -----
  k_head<<<(BB + 3) / 4, 256, 0, stream>>>(uemb, user_ids, item_ids, out2,
                                           pw1, pb1, pw2, pb2, out, BB);
}

// Round 2
// 878.415 us; speedup vs baseline: 1.1349x; 1.1349x over previous
//
#include <hip/hip_runtime.h>
#include <hip/hip_fp16.h>
#include <math.h>

// Problem constants (match reference)
static constexpr int ND  = 150000;   // total nodes
static constexpr int NUU = 100000;   // num users
static constexpr int BB  = 16384;    // batch
static constexpr int EE  = 2000000;  // edges (before self loops)
static constexpr int ETOT = EE + ND; // edges incl self loops

// ---------------- wave helpers ----------------
__device__ __forceinline__ float wsum64(float v){
#pragma unroll
  for (int d = 32; d > 0; d >>= 1) v += __shfl_xor(v, d, 64);
  return v;
}
__device__ __forceinline__ float wmax64(float v){
#pragma unroll
  for (int d = 32; d > 0; d >>= 1) v = fmaxf(v, __shfl_xor(v, d, 64));
  return v;
}

// ---------------- input scatter (fp16 x) ----------------
__global__ __launch_bounds__(256) void k_users(const int* __restrict__ uids,
    const float* __restrict__ uemb, __half* __restrict__ x){
  int t = blockIdx.x * 256 + threadIdx.x;
  if (t >= BB * 64) return;
  int b = t >> 6, c = t & 63;
  int uid = uids[b];
  x[(size_t)uid * 128 + c] = __float2half(uemb[(size_t)uid * 64 + c]);
}

__global__ __launch_bounds__(256) void k_items(const float* __restrict__ content,
    const float* __restrict__ cpw, const float* __restrict__ cpb,
    const float* __restrict__ iemb, const int* __restrict__ iids,
    __half* __restrict__ x){
  int c  = threadIdx.x & 63;
  int rr = threadIdx.x >> 6;
  int r0 = blockIdx.x * 16 + rr * 4;
  float acc[4] = {0.f, 0.f, 0.f, 0.f};
  for (int k = 0; k < 256; k++) {
    float wv = cpw[k * 64 + c];
#pragma unroll
    for (int i = 0; i < 4; i++)
      acc[i] = fmaf(content[(size_t)(r0 + i) * 256 + k], wv, acc[i]);
  }
#pragma unroll
  for (int i = 0; i < 4; i++) {
    int r = r0 + i;
    if (r >= BB) continue;
    int iid = iids[r];
    size_t node = (size_t)(NUU + iid);
    x[node * 128 + 64 + c] = __float2half(acc[i] + cpb[c]);
    x[node * 128 + c]      = __float2half(iemb[(size_t)iid * 64 + c]);
  }
}

// ---------------- CSR build (by dst) ----------------
__global__ __launch_bounds__(256) void k_count(const int* __restrict__ ei,
    int* __restrict__ deg){
  int t = blockIdx.x * 256 + threadIdx.x;
  if (t >= ETOT) return;
  int dst = (t < EE) ? ei[EE + t] : (t - EE);
  atomicAdd(&deg[dst], 1);
}

__global__ __launch_bounds__(1024) void k_scan(const int* __restrict__ deg,
    int* __restrict__ offs, int* __restrict__ cursor, int n){
  __shared__ int wsums[16];
  __shared__ int carry_s;
  int tid = threadIdx.x;
  int lane = tid & 63, w = tid >> 6;
  if (tid == 0) carry_s = 0;
  __syncthreads();
  int nchunks = (n + 4095) / 4096;
  for (int c = 0; c < nchunks; c++) {
    int idx = c * 4096 + tid * 4;
    int4 v = make_int4(0, 0, 0, 0);
    if (idx + 3 < n) v = *(const int4*)(deg + idx);
    else {
      if (idx     < n) v.x = deg[idx];
      if (idx + 1 < n) v.y = deg[idx + 1];
      if (idx + 2 < n) v.z = deg[idx + 2];
      if (idx + 3 < n) v.w = deg[idx + 3];
    }
    int s = v.x + v.y + v.z + v.w;
    int x = s;
#pragma unroll
    for (int d = 1; d < 64; d <<= 1) { int t2 = __shfl_up(x, d, 64); if (lane >= d) x += t2; }
    if (lane == 63) wsums[w] = x;
    __syncthreads();
    if (w == 0) {
      int t3 = (lane < 16) ? wsums[lane] : 0;
#pragma unroll
      for (int d = 1; d < 16; d <<= 1) { int t2 = __shfl_up(t3, d, 64); if (lane >= d) t3 += t2; }
      if (lane < 16) wsums[lane] = t3;
    }
    __syncthreads();
    int chunk_total = wsums[15];
    int base = carry_s + ((w > 0) ? wsums[w - 1] : 0) + (x - s);
    int4 o; o.x = base; o.y = base + v.x; o.z = o.y + v.y; o.w = o.z + v.z;
    if (idx + 3 < n) { *(int4*)(offs + idx) = o; *(int4*)(cursor + idx) = o; }
    else {
      if (idx     < n) { offs[idx]     = o.x; cursor[idx]     = o.x; }
      if (idx + 1 < n) { offs[idx + 1] = o.y; cursor[idx + 1] = o.y; }
      if (idx + 2 < n) { offs[idx + 2] = o.z; cursor[idx + 2] = o.z; }
      if (idx + 3 < n) { offs[idx + 3] = o.w; cursor[idx + 3] = o.w; }
    }
    __syncthreads();
    if (tid == 0) carry_s += chunk_total;
    __syncthreads();
  }
  if (threadIdx.x == 0) offs[n] = carry_s;
}

__global__ __launch_bounds__(256) void k_fill(const int* __restrict__ ei,
    int* __restrict__ cursor, int* __restrict__ csr){
  int t = blockIdx.x * 256 + threadIdx.x;
  if (t >= ETOT) return;
  int src, dst;
  if (t < EE) { src = ei[t]; dst = ei[EE + t]; }
  else        { src = dst = t - EE; }
  int pos = atomicAdd(&cursor[dst], 1);
  csr[pos] = src;
}

// ---------------- GEMM: C[M,Ncols](f16) = A[M,128](f16) @ W[128,Ncols](f32) ----------------
// 64x64 tile, BK=64 two-stage, 4x4 reg tile, LDS stride 68.
// Fused epilogue: per-row attention scores for head = blockIdx.y (Ncols = H*64).
template<int H>
__global__ __launch_bounds__(256) void k_gemm_sc(const __half* __restrict__ A,
    const float* __restrict__ W, __half* __restrict__ C,
    float* __restrict__ als, float* __restrict__ ald,
    const float* __restrict__ asrc, const float* __restrict__ adst,
    int M, int Ncols){
  __shared__ __align__(16) float As[64 * 68];
  __shared__ __align__(16) float Ws[64 * 68];
  int tid = threadIdx.x;
  int head = blockIdx.y;
  int m_base = blockIdx.x * 64;
  int n_base = head * 64;
  int tm = (tid >> 4) * 4;
  int tn = (tid & 15) * 4;
  float acc[4][4];
#pragma unroll
  for (int i = 0; i < 4; i++)
#pragma unroll
    for (int j = 0; j < 4; j++) acc[i][j] = 0.f;

  int lm = tid >> 2;   // 0..63
  int lq = tid & 3;    // 0..3
  for (int ks = 0; ks < 128; ks += 64) {
    // stage A (fp16 -> fp32 LDS): 16 halves per thread
    {
      int gm = m_base + lm;
      union { uint4 u; __half2 h[4]; } r0, r1;
      r0.u = make_uint4(0,0,0,0); r1.u = make_uint4(0,0,0,0);
      if (gm < M) {
        const __half* ap = A + (size_t)gm * 128 + ks + lq * 16;
        r0.u = *(const uint4*)ap;
        r1.u = *(const uint4*)(ap + 8);
      }
      float* dst = As + lm * 68 + lq * 16;
      float2 f0 = __half22float2(r0.h[0]), f1 = __half22float2(r0.h[1]);
      float2 f2 = __half22float2(r0.h[2]), f3 = __half22float2(r0.h[3]);
      *(float4*)(dst)     = make_float4(f0.x, f0.y, f1.x, f1.y);
      *(float4*)(dst + 4) = make_float4(f2.x, f2.y, f3.x, f3.y);
      f0 = __half22float2(r1.h[0]); f1 = __half22float2(r1.h[1]);
      f2 = __half22float2(r1.h[2]); f3 = __half22float2(r1.h[3]);
      *(float4*)(dst + 8)  = make_float4(f0.x, f0.y, f1.x, f1.y);
      *(float4*)(dst + 12) = make_float4(f2.x, f2.y, f3.x, f3.y);
    }
    // stage W (fp32)
#pragma unroll
    for (int p = 0; p < 4; p++) {
      int n4 = lq + p * 4;
      float4 v = *(const float4*)(W + (size_t)(ks + lm) * Ncols + n_base + n4 * 4);
      *(float4*)(Ws + lm * 68 + n4 * 4) = v;
    }
    __syncthreads();
#pragma unroll
    for (int kk = 0; kk < 64; kk += 4) {
      float a_arr[4][4], w_arr[4][4];
#pragma unroll
      for (int i = 0; i < 4; i++) {
        float4 a = *(const float4*)(As + (tm + i) * 68 + kk);
        a_arr[i][0] = a.x; a_arr[i][1] = a.y; a_arr[i][2] = a.z; a_arr[i][3] = a.w;
      }
#pragma unroll
      for (int q = 0; q < 4; q++) {
        float4 wv = *(const float4*)(Ws + (kk + q) * 68 + tn);
        w_arr[q][0] = wv.x; w_arr[q][1] = wv.y; w_arr[q][2] = wv.z; w_arr[q][3] = wv.w;
      }
#pragma unroll
      for (int q = 0; q < 4; q++)
#pragma unroll
        for (int i = 0; i < 4; i++)
#pragma unroll
          for (int j = 0; j < 4; j++)
            acc[i][j] = fmaf(a_arr[i][q], w_arr[q][j], acc[i][j]);
    }
    __syncthreads();
  }
  // epilogue: C fp16 + fused scores
  float ssrc[4], sdst[4];
  float a_s[4], a_d[4];
#pragma unroll
  for (int j = 0; j < 4; j++) {
    a_s[j] = asrc[head * 64 + tn + j];
    a_d[j] = adst[head * 64 + tn + j];
  }
#pragma unroll
  for (int i = 0; i < 4; i++) {
    int gm = m_base + tm + i;
    ssrc[i] = acc[i][0]*a_s[0] + acc[i][1]*a_s[1] + acc[i][2]*a_s[2] + acc[i][3]*a_s[3];
    sdst[i] = acc[i][0]*a_d[0] + acc[i][1]*a_d[1] + acc[i][2]*a_d[2] + acc[i][3]*a_d[3];
    if (gm < M) {
      __half2 h0 = __floats2half2_rn(acc[i][0], acc[i][1]);
      __half2 h1 = __floats2half2_rn(acc[i][2], acc[i][3]);
      union { uint2 u; __half2 h[2]; } pk; pk.h[0] = h0; pk.h[1] = h1;
      *(uint2*)(C + (size_t)gm * Ncols + n_base + tn) = pk.u;
    }
  }
#pragma unroll
  for (int d = 1; d < 16; d <<= 1) {
#pragma unroll
    for (int i = 0; i < 4; i++) {
      ssrc[i] += __shfl_xor(ssrc[i], d, 64);
      sdst[i] += __shfl_xor(sdst[i], d, 64);
    }
  }
  if ((tid & 15) == 0) {
#pragma unroll
    for (int i = 0; i < 4; i++) {
      int gm = m_base + tm + i;
      if (gm < M) {
        als[(size_t)gm * H + head] = ssrc[i];
        ald[(size_t)gm * H + head] = sdst[i];
      }
    }
  }
}

// ---------------- GAT aggregation, H=2: one wave per dst, lane = (head, half2-channel) ----------------
__global__ __launch_bounds__(256) void k_agg2(const __half* __restrict__ xw,
    const float* __restrict__ als, const float* __restrict__ ald,
    const int* __restrict__ offs, const int* __restrict__ csr,
    const float* __restrict__ bias, __half* __restrict__ out, int n){
  int gw = (blockIdx.x * 256 + threadIdx.x) >> 6;
  int lane = threadIdx.x & 63;
  if (gw >= n) return;
  int e0 = offs[gw], e1 = offs[gw + 1];
  float ald0 = ald[(size_t)gw * 2], ald1 = ald[(size_t)gw * 2 + 1];
  float m0 = -INFINITY, m1 = -INFINITY, d0 = 0.f, d1 = 0.f;
  float accx = 0.f, accy = 0.f;
  for (int base = e0; base < e1; base += 64) {
    int e = base + lane;
    bool valid = (e < e1);
    int src = valid ? csr[e] : 0;
    int cnt = (e1 - base < 64) ? (e1 - base) : 64;
    float s0, s1;
    if (valid) {
      float2 a = *(const float2*)(als + (size_t)src * 2);
      float v0 = a.x + ald0, v1 = a.y + ald1;
      s0 = (v0 > 0.f) ? v0 : 0.2f * v0;
      s1 = (v1 > 0.f) ? v1 : 0.2f * v1;
    } else { s0 = -INFINITY; s1 = -INFINITY; }
    float mn0 = fmaxf(m0, wmax64(s0));
    float mn1 = fmaxf(m1, wmax64(s1));
    float sc0 = expf(m0 - mn0), sc1 = expf(m1 - mn1);
    float p0 = valid ? expf(s0 - mn0) : 0.f;
    float p1 = valid ? expf(s1 - mn1) : 0.f;
    d0 = d0 * sc0 + wsum64(p0);
    d1 = d1 * sc1 + wsum64(p1);
    float mysc = (lane < 32) ? sc0 : sc1;
    accx *= mysc; accy *= mysc;
    m0 = mn0; m1 = mn1;
    for (int j = 0; j < cnt; j++) {
      int sj = __shfl(src, j, 64);
      float pj0 = __shfl(p0, j, 64);
      float pj1 = __shfl(p1, j, 64);
      float pj = (lane < 32) ? pj0 : pj1;
      __half2 hv = *(const __half2*)(xw + (size_t)sj * 128 + 2 * lane);
      float2 fv = __half22float2(hv);
      accx = fmaf(pj, fv.x, accx);
      accy = fmaf(pj, fv.y, accy);
    }
  }
  float den = (lane < 32) ? d0 : d1;
  float inv = 1.f / (den + 1e-16f);
  float2 b = *(const float2*)(bias + 2 * lane);
  float vx = accx * inv + b.x;
  float vy = accy * inv + b.y;
  vx = (vx > 0.f) ? vx : expm1f(vx);   // elu
  vy = (vy > 0.f) ? vy : expm1f(vy);
  *(__half2*)(out + (size_t)gw * 128 + 2 * lane) = __floats2half2_rn(vx, vy);
}

// ---------------- GAT aggregation, H=1: one wave per dst, 2 edges per instr ----------------
__global__ __launch_bounds__(256) void k_agg1(const __half* __restrict__ xw,
    const float* __restrict__ als, const float* __restrict__ ald,
    const int* __restrict__ offs, const int* __restrict__ csr,
    const float* __restrict__ bias, __half* __restrict__ out, int n){
  int gw = (blockIdx.x * 256 + threadIdx.x) >> 6;
  int lane = threadIdx.x & 63;
  if (gw >= n) return;
  int e0 = offs[gw], e1 = offs[gw + 1];
  float aldd = ald[gw];
  float m = -INFINITY, den = 0.f;
  float accx = 0.f, accy = 0.f;
  int half_id = lane >> 5;
  int c = (lane & 31) * 2;
  for (int base = e0; base < e1; base += 64) {
    int e = base + lane;
    bool valid = (e < e1);
    int src = valid ? csr[e] : 0;
    int cnt = (e1 - base < 64) ? (e1 - base) : 64;
    float s;
    if (valid) {
      float v = als[src] + aldd;
      s = (v > 0.f) ? v : 0.2f * v;
    } else s = -INFINITY;
    float mn = fmaxf(m, wmax64(s));
    float sc = expf(m - mn);
    float p = valid ? expf(s - mn) : 0.f;
    den = den * sc + wsum64(p);
    accx *= sc; accy *= sc;
    m = mn;
    for (int j = 0; j < cnt; j += 2) {
      int jj = j + half_id;                 // lanes 0-31: edge j; 32-63: edge j+1
      int sj = __shfl(src, jj, 64);         // p==0 / src==0 for jj==cnt (odd tail) — harmless
      float pj = __shfl(p, jj, 64);
      __half2 hv = *(const __half2*)(xw + (size_t)sj * 64 + c);
      float2 fv = __half22float2(hv);
      accx = fmaf(pj, fv.x, accx);
      accy = fmaf(pj, fv.y, accy);
    }
  }
  accx += __shfl_xor(accx, 32, 64);
  accy += __shfl_xor(accy, 32, 64);
  if (lane < 32) {
    float inv = 1.f / (den + 1e-16f);
    float2 b = *(const float2*)(bias + c);
    float vx = accx * inv + b.x;
    float vy = accy * inv + b.y;
    *(__half2*)(out + (size_t)gw * 64 + c) = __floats2half2_rn(vx, vy);
  }
}

// ---------------- prediction head: one wave per batch row ----------------
__global__ __launch_bounds__(256) void k_head(const float* __restrict__ uemb,
    const int* __restrict__ uids, const int* __restrict__ iids,
    const __half* __restrict__ x2, const float* __restrict__ pw1,
    const float* __restrict__ pb1, const float* __restrict__ pw2,
    const float* __restrict__ pb2, float* __restrict__ out, int B){
  __shared__ __align__(16) float pw1_s[192 * 64];  // 48KB
  __shared__ float comb_s[4][192];
  for (int i = threadIdx.x; i < 192 * 64 / 4; i += 256)
    ((float4*)pw1_s)[i] = ((const float4*)pw1)[i];
  int w = threadIdx.x >> 6, lane = threadIdx.x & 63;
  int b = blockIdx.x * 4 + w;
  if (b < B) {
    int uid = uids[b], iid = iids[b];
    comb_s[w][lane]       = uemb[(size_t)uid * 64 + lane];
    comb_s[w][64 + lane]  = __half2float(x2[(size_t)(NUU + iid) * 64 + lane]);
    comb_s[w][128 + lane] = __half2float(x2[(size_t)uid * 64 + lane]);
  }
  __syncthreads();
  if (b >= B) return;
  float acc = pb1[lane];
#pragma unroll 8
  for (int j = 0; j < 192; j++)
    acc = fmaf(comb_s[w][j], pw1_s[j * 64 + lane], acc);
  acc = fmaxf(acc, 0.f);
  float prod = wsum64(acc * pw2[lane]);
  if (lane == 0) out[b] = prod + pb2[0];
}

// ---------------- launcher ----------------
extern "C" void kernel_launch(void* const* d_in, const int* in_sizes, int n_in,
                              void* d_out, int out_size, void* d_ws, size_t ws_size,
                              hipStream_t stream) {
  (void)in_sizes; (void)n_in; (void)out_size; (void)ws_size;
  const int*   user_ids = (const int*)  d_in[0];
  const int*   item_ids = (const int*)  d_in[1];
  const float* content  = (const float*)d_in[2];
  const int*   edge_idx = (const int*)  d_in[3];
  const float* uemb     = (const float*)d_in[4];
  const float* iemb     = (const float*)d_in[5];
  const float* cp_w     = (const float*)d_in[6];
  const float* cp_b     = (const float*)d_in[7];
  const float* w1       = (const float*)d_in[8];
  const float* asrc1    = (const float*)d_in[9];
  const float* adst1    = (const float*)d_in[10];
  const float* b1       = (const float*)d_in[11];
  const float* w2       = (const float*)d_in[12];
  const float* asrc2    = (const float*)d_in[13];
  const float* adst2    = (const float*)d_in[14];
  const float* b2       = (const float*)d_in[15];
  const float* pw1      = (const float*)d_in[16];
  const float* pb1      = (const float*)d_in[17];
  const float* pw2      = (const float*)d_in[18];
  const float* pb2      = (const float*)d_in[19];
  float* out = (float*)d_out;

  // workspace layout (fp16 intermediates, ~90 MB)
  __half* x   = (__half*)d_ws;                 // [ND,128] f16; reused as x1 (layer-1 out)
  __half* xw  = x + (size_t)ND * 128;          // [ND,128] f16 xw1; L2: xw2=[0:ND*64), out2=[ND*64:)
  float* als  = (float*)(xw + (size_t)ND * 128); // [ND,2]
  float* ald  = als + (size_t)ND * 2;          // [ND,2]
  int* deg    = (int*)(ald + (size_t)ND * 2);  // [ND]
  int* offs   = deg + ND;                      // [ND+4]
  int* cursor = offs + ND + 4;                 // [ND]
  int* csr    = cursor + ND;                   // [ETOT]
  __half* out2 = xw + (size_t)ND * 64;

  hipMemsetAsync(x, 0, (size_t)ND * 128 * sizeof(__half), stream);
  hipMemsetAsync(deg, 0, ND * sizeof(int), stream);

  k_users<<<(BB * 64 + 255) / 256, 256, 0, stream>>>(user_ids, uemb, x);
  k_items<<<BB / 16, 256, 0, stream>>>(content, cp_w, cp_b, iemb, item_ids, x);

  k_count<<<(ETOT + 255) / 256, 256, 0, stream>>>(edge_idx, deg);
  k_scan<<<1, 1024, 0, stream>>>(deg, offs, cursor, ND);
  k_fill<<<(ETOT + 255) / 256, 256, 0, stream>>>(edge_idx, cursor, csr);

  // ----- GAT layer 1 (H=2) -----
  k_gemm_sc<2><<<dim3((ND + 63) / 64, 2), 256, 0, stream>>>(x, w1, xw, als, ald,
                                                            asrc1, adst1, ND, 128);
  k_agg2<<<(ND * 64 + 255) / 256, 256, 0, stream>>>(xw, als, ald, offs, csr, b1, x, ND);

  // ----- GAT layer 2 (H=1) -----
  k_gemm_sc<1><<<dim3((ND + 63) / 64, 1), 256, 0, stream>>>(x, w2, xw, als, ald,
                                                            asrc2, adst2, ND, 64);
  k_agg1<<<(ND * 64 + 255) / 256, 256, 0, stream>>>(xw, als, ald, offs, csr, b2, out2, ND);

  // ----- head -----
  k_head<<<(BB + 3) / 4, 256, 0, stream>>>(uemb, user_ids, item_ids, out2,
                                           pw1, pb1, pw2, pb2, out, BB);
}

// Round 3
// 685.675 us; speedup vs baseline: 1.4539x; 1.2811x over previous
//
#include <hip/hip_runtime.h>
#include <hip/hip_fp16.h>
#include <math.h>

// Problem constants (match reference)
static constexpr int ND  = 150000;   // total nodes
static constexpr int NUU = 100000;   // num users
static constexpr int BB  = 16384;    // batch
static constexpr int EE  = 2000000;  // edges (before self loops)
static constexpr int ETOT = EE + ND; // edges incl self loops
static constexpr int NBLK_SCAN = (ND + 1023) / 1024;  // 147

typedef _Float16 h8 __attribute__((ext_vector_type(8)));
typedef float    f4 __attribute__((ext_vector_type(4)));

// ---------------- wave helpers ----------------
__device__ __forceinline__ float wsum64(float v){
#pragma unroll
  for (int d = 32; d > 0; d >>= 1) v += __shfl_xor(v, d, 64);
  return v;
}
__device__ __forceinline__ int wsum64i(int v){
#pragma unroll
  for (int d = 32; d > 0; d >>= 1) v += __shfl_xor(v, d, 64);
  return v;
}

// ---------------- weight prep ----------------
// Wt1[n][k] = w1[k][n] fp16 (n<128,k<128); Wt2[n][k] = w2[k][n] fp16 (n<64,k<128)
__global__ __launch_bounds__(256) void k_conv(const float* __restrict__ w1,
    const float* __restrict__ w2, __half* __restrict__ Wt1, __half* __restrict__ Wt2){
  int t = blockIdx.x * 256 + threadIdx.x;
  if (t < 16384) {
    int n = t >> 7, k = t & 127;
    Wt1[t] = __float2half(w1[k * 128 + n]);
  } else if (t < 24576) {
    int u = t - 16384;
    int n = u >> 7, k = u & 127;
    Wt2[u] = __float2half(w2[k * 64 + n]);
  }
}

// wa = W @ a^T : wa1s[k*2+h] = sum_c w1[k][h*64+c]*asrc1[h*64+c]; similarly d; wa2 for layer2
__global__ __launch_bounds__(128) void k_wa(const float* __restrict__ w1,
    const float* __restrict__ asrc1, const float* __restrict__ adst1,
    const float* __restrict__ w2, const float* __restrict__ asrc2,
    const float* __restrict__ adst2,
    float* __restrict__ wa1s, float* __restrict__ wa1d,
    float* __restrict__ wa2s, float* __restrict__ wa2d){
  int k = threadIdx.x;  // 0..127
  float s0 = 0.f, s1 = 0.f, d0 = 0.f, d1 = 0.f, s2 = 0.f, d2 = 0.f;
  for (int c = 0; c < 64; c++) {
    float wA = w1[k * 128 + c];
    float wB = w1[k * 128 + 64 + c];
    s0 = fmaf(wA, asrc1[c], s0);       d0 = fmaf(wA, adst1[c], d0);
    s1 = fmaf(wB, asrc1[64 + c], s1);  d1 = fmaf(wB, adst1[64 + c], d1);
    float wC = w2[k * 64 + c];
    s2 = fmaf(wC, asrc2[c], s2);       d2 = fmaf(wC, adst2[c], d2);
  }
  wa1s[k * 2] = s0; wa1s[k * 2 + 1] = s1;
  wa1d[k * 2] = d0; wa1d[k * 2 + 1] = d1;
  wa2s[k] = s2; wa2d[k] = d2;
}

// ---------------- input scatter (fp16 x) + fused layer-1 scores ----------------
__global__ __launch_bounds__(256) void k_users(const int* __restrict__ uids,
    const float* __restrict__ uemb, __half* __restrict__ x,
    const float* __restrict__ wa1s, const float* __restrict__ wa1d,
    float* __restrict__ als1, float* __restrict__ ald1){
  int t = blockIdx.x * 256 + threadIdx.x;
  int b = t >> 6, c = t & 63;          // one wave per row
  int uid = uids[b];
  float u = uemb[(size_t)uid * 64 + c];
  x[(size_t)uid * 128 + c] = __float2half(u);
  float2 ws = *(const float2*)(wa1s + 2 * c);
  float2 wd = *(const float2*)(wa1d + 2 * c);
  float s0 = wsum64(u * ws.x);
  float s1 = wsum64(u * ws.y);
  float d0 = wsum64(u * wd.x);
  float d1 = wsum64(u * wd.y);
  if (c == 0) {
    *(float2*)(als1 + (size_t)uid * 2) = make_float2(s0, s1);
    *(float2*)(ald1 + (size_t)uid * 2) = make_float2(d0, d1);
  }
}

__global__ __launch_bounds__(256) void k_items(const float* __restrict__ content,
    const float* __restrict__ cpw, const float* __restrict__ cpb,
    const float* __restrict__ iemb, const int* __restrict__ iids,
    __half* __restrict__ x,
    const float* __restrict__ wa1s, const float* __restrict__ wa1d,
    float* __restrict__ als1, float* __restrict__ ald1){
  int c  = threadIdx.x & 63;
  int rr = threadIdx.x >> 6;
  int r0 = blockIdx.x * 16 + rr * 4;
  float acc[4] = {0.f, 0.f, 0.f, 0.f};
  for (int k = 0; k < 256; k++) {
    float wv = cpw[k * 64 + c];
#pragma unroll
    for (int i = 0; i < 4; i++)
      acc[i] = fmaf(content[(size_t)(r0 + i) * 256 + k], wv, acc[i]);
  }
  float2 wsL = *(const float2*)(wa1s + 2 * c);
  float2 wdL = *(const float2*)(wa1d + 2 * c);
  float2 wsH = *(const float2*)(wa1s + 128 + 2 * c);
  float2 wdH = *(const float2*)(wa1d + 128 + 2 * c);
#pragma unroll
  for (int i = 0; i < 4; i++) {
    int r = r0 + i;
    if (r >= BB) continue;
    int iid = iids[r];
    size_t node = (size_t)(NUU + iid);
    float hi = acc[i] + cpb[c];
    float lo = iemb[(size_t)iid * 64 + c];
    x[node * 128 + 64 + c] = __float2half(hi);
    x[node * 128 + c]      = __float2half(lo);
    float s0 = wsum64(lo * wsL.x + hi * wsH.x);
    float s1 = wsum64(lo * wsL.y + hi * wsH.y);
    float d0 = wsum64(lo * wdL.x + hi * wdH.x);
    float d1 = wsum64(lo * wdL.y + hi * wdH.y);
    if (c == 0) {
      *(float2*)(als1 + node * 2) = make_float2(s0, s1);
      *(float2*)(ald1 + node * 2) = make_float2(d0, d1);
    }
  }
}

// ---------------- CSR build (by dst) ----------------
__global__ __launch_bounds__(256) void k_count(const int* __restrict__ ei,
    int* __restrict__ deg){
  int t = blockIdx.x * 256 + threadIdx.x;
  if (t >= ETOT) return;
  int dst = (t < EE) ? ei[EE + t] : (t - EE);
  atomicAdd(&deg[dst], 1);
}

// multi-block scan: 1) per-block sums  2) scan of block sums  3) per-block rescan
__global__ __launch_bounds__(256) void k_scan1(const int* __restrict__ deg,
    int* __restrict__ bsums, int n){
  __shared__ int wsums[4];
  int tid = threadIdx.x, lane = tid & 63, w = tid >> 6;
  int idx = blockIdx.x * 1024 + tid * 4;
  int4 v = make_int4(0, 0, 0, 0);
  if (idx < n) v = *(const int4*)(deg + idx);     // n % 4 == 0
  int s = wsum64i(v.x + v.y + v.z + v.w);
  if (lane == 0) wsums[w] = s;
  __syncthreads();
  if (tid == 0) bsums[blockIdx.x] = wsums[0] + wsums[1] + wsums[2] + wsums[3];
}

__global__ void k_scan2(int* __restrict__ bsums, int nb, int* __restrict__ offs_end){
  int lane = threadIdx.x;   // 64 threads
  int carry = 0;
  for (int c0 = 0; c0 < nb; c0 += 64) {
    int i = c0 + lane;
    int v = (i < nb) ? bsums[i] : 0;
    int x = v;
#pragma unroll
    for (int d = 1; d < 64; d <<= 1) { int t = __shfl_up(x, d, 64); if (lane >= d) x += t; }
    if (i < nb) bsums[i] = carry + x - v;         // exclusive
    carry += __shfl(x, 63, 64);
  }
  if (lane == 0) *offs_end = carry;
}

__global__ __launch_bounds__(256) void k_scan3(const int* __restrict__ deg,
    const int* __restrict__ bsums, int* __restrict__ offs, int* __restrict__ cursor, int n){
  __shared__ int wsums[4];
  int tid = threadIdx.x, lane = tid & 63, w = tid >> 6;
  int idx = blockIdx.x * 1024 + tid * 4;
  int4 v = make_int4(0, 0, 0, 0);
  if (idx < n) v = *(const int4*)(deg + idx);
  int s = v.x + v.y + v.z + v.w;
  int x = s;
#pragma unroll
  for (int d = 1; d < 64; d <<= 1) { int t = __shfl_up(x, d, 64); if (lane >= d) x += t; }
  if (lane == 63) wsums[w] = x;
  __syncthreads();
  if (tid == 0) { int a = 0; for (int i = 0; i < 4; i++) { int t = wsums[i]; wsums[i] = a; a += t; } }
  __syncthreads();
  int base = bsums[blockIdx.x] + wsums[w] + (x - s);
  int4 o; o.x = base; o.y = base + v.x; o.z = o.y + v.y; o.w = o.z + v.z;
  if (idx < n) { *(int4*)(offs + idx) = o; *(int4*)(cursor + idx) = o; }
}

__global__ __launch_bounds__(256) void k_fill(const int* __restrict__ ei,
    int* __restrict__ cursor, int* __restrict__ csr){
  int t = blockIdx.x * 256 + threadIdx.x;
  if (t >= ETOT) return;
  int src, dst;
  if (t < EE) { src = ei[t]; dst = ei[EE + t]; }
  else        { src = dst = t - EE; }
  int pos = atomicAdd(&cursor[dst], 1);
  csr[pos] = src;
}

// ---------------- MFMA fp16 GEMM: C[M,N](f16) = A[M,128](f16) @ Bt[N,128]^T ----------------
// one wave = 32 rows x N cols; direct global->VGPR (A read once, Bt L1-resident)
template<int NT>   // N = NT*16
__global__ __launch_bounds__(256) void k_mfma(const __half* __restrict__ A,
    const __half* __restrict__ Bt, __half* __restrict__ C, int M){
  constexpr int N = NT * 16;
  int wid  = (blockIdx.x * 256 + threadIdx.x) >> 6;
  int lane = threadIdx.x & 63;
  int q = lane >> 4, mr = lane & 15;
  int r0 = wid * 32;
  if (r0 >= M) return;
  int row0 = min(r0 + mr, M - 1);
  int row1 = min(r0 + 16 + mr, M - 1);
  f4 acc[2][NT];
#pragma unroll
  for (int i = 0; i < 2; i++)
#pragma unroll
    for (int j = 0; j < NT; j++) acc[i][j] = (f4)0.f;
#pragma unroll
  for (int ks = 0; ks < 4; ks++) {
    int ko = ks * 32 + q * 8;
    h8 a0 = *(const h8*)(A + (size_t)row0 * 128 + ko);
    h8 a1 = *(const h8*)(A + (size_t)row1 * 128 + ko);
#pragma unroll
    for (int nt = 0; nt < NT; nt++) {
      h8 b = *(const h8*)(Bt + (size_t)(nt * 16 + mr) * 128 + ko);
      acc[0][nt] = __builtin_amdgcn_mfma_f32_16x16x32_f16(a0, b, acc[0][nt], 0, 0, 0);
      acc[1][nt] = __builtin_amdgcn_mfma_f32_16x16x32_f16(a1, b, acc[1][nt], 0, 0, 0);
    }
  }
#pragma unroll
  for (int mt = 0; mt < 2; mt++)
#pragma unroll
    for (int r = 0; r < 4; r++) {
      int row = r0 + mt * 16 + q * 4 + r;
      if (row < M) {
#pragma unroll
        for (int nt = 0; nt < NT; nt++)
          C[(size_t)row * N + nt * 16 + mr] = __float2half(acc[mt][nt][r]);
      }
    }
}

// ---------------- GAT aggregation, H=2 (layer 1) ----------------
// one wave per dst; fused: bias+ELU epilogue, layer-2 score computation
__global__ __launch_bounds__(256) void k_agg2(const __half* __restrict__ xw,
    const float* __restrict__ als, const float* __restrict__ ald,
    const int* __restrict__ offs, const int* __restrict__ csr,
    const float* __restrict__ bias, __half* __restrict__ out,
    const float* __restrict__ wa2s, const float* __restrict__ wa2d,
    float* __restrict__ als2, float* __restrict__ ald2, int n){
  int gw = (blockIdx.x * 256 + threadIdx.x) >> 6;
  int lane = threadIdx.x & 63;
  if (gw >= n) return;
  int e0 = offs[gw], e1 = offs[gw + 1];
  float2 aldv = *(const float2*)(ald + (size_t)gw * 2);
  bool lo = lane < 32;
  float den0 = 0.f, den1 = 0.f, accx = 0.f, accy = 0.f;
  const __half2* xwp = (const __half2*)xw;
  for (int base = e0; base < e1; base += 64) {
    int e = base + lane;
    bool valid = (e < e1);
    int src = valid ? csr[e] : 0;
    float p0 = 0.f, p1 = 0.f;
    if (valid) {
      float2 a = *(const float2*)(als + (size_t)src * 2);
      float v0 = a.x + aldv.x, v1 = a.y + aldv.y;
      v0 = (v0 > 0.f) ? v0 : 0.2f * v0;
      v1 = (v1 > 0.f) ? v1 : 0.2f * v1;
      p0 = __expf(v0); p1 = __expf(v1);
    }
    den0 += wsum64(p0);
    den1 += wsum64(p1);
    int cnt = min(e1 - base, 64);
    for (int j0 = 0; j0 < cnt; j0 += 8) {
      __half2 hv[8]; float pj[8];
#pragma unroll
      for (int u = 0; u < 8; u++) {
        int jj = j0 + u;                         // jj <= 63 always
        int sj = __shfl(src, jj, 64);
        float q0 = __shfl(p0, jj, 64);
        float q1 = __shfl(p1, jj, 64);
        pj[u] = lo ? q0 : q1;
        hv[u] = xwp[(size_t)sj * 64 + lane];     // 4B per lane, 256B per wave
      }
#pragma unroll
      for (int u = 0; u < 8; u++) {
        float2 fv = __half22float2(hv[u]);
        accx = fmaf(pj[u], fv.x, accx);
        accy = fmaf(pj[u], fv.y, accy);
      }
    }
  }
  float den = (lo ? den0 : den1) + 1e-16f;
  float inv = 1.f / den;
  float2 b = *(const float2*)(bias + 2 * lane);
  float vx = accx * inv + b.x;
  float vy = accy * inv + b.y;
  vx = (vx > 0.f) ? vx : expm1f(vx);             // elu
  vy = (vy > 0.f) ? vy : expm1f(vy);
  *(__half2*)(out + (size_t)gw * 128 + 2 * lane) = __floats2half2_rn(vx, vy);
  // fused layer-2 scores (from fp32 values): als2 = x1 . (W2 @ asrc2)
  float2 ws = *(const float2*)(wa2s + 2 * lane);
  float2 wd = *(const float2*)(wa2d + 2 * lane);
  float s_s = wsum64(vx * ws.x + vy * ws.y);
  float s_d = wsum64(vx * wd.x + vy * wd.y);
  if (lane == 0) { als2[gw] = s_s; ald2[gw] = s_d; }
}

// ---------------- GAT aggregation, H=1 (layer 2): 2 edges per instruction ----------------
__global__ __launch_bounds__(256) void k_agg1(const __half* __restrict__ xw,
    const float* __restrict__ als, const float* __restrict__ ald,
    const int* __restrict__ offs, const int* __restrict__ csr,
    const float* __restrict__ bias, __half* __restrict__ out, int n){
  int gw = (blockIdx.x * 256 + threadIdx.x) >> 6;
  int lane = threadIdx.x & 63;
  if (gw >= n) return;
  int e0 = offs[gw], e1 = offs[gw + 1];
  float aldd = ald[gw];
  float den = 0.f, accx = 0.f, accy = 0.f;
  int hid = lane >> 5;
  int c = lane & 31;
  const __half2* xwp = (const __half2*)xw;
  for (int base = e0; base < e1; base += 64) {
    int e = base + lane;
    bool valid = (e < e1);
    int src = valid ? csr[e] : 0;
    float p = 0.f;
    if (valid) {
      float v = als[src] + aldd;
      v = (v > 0.f) ? v : 0.2f * v;
      p = __expf(v);
    }
    den += wsum64(p);
    int cnt = min(e1 - base, 64);
    for (int j0 = 0; j0 < cnt; j0 += 16) {
      __half2 hv[8]; float pj[8];
#pragma unroll
      for (int u = 0; u < 8; u++) {
        int jj = j0 + 2 * u + hid;               // jj <= 63 always
        int sj = __shfl(src, jj, 64);
        pj[u] = __shfl(p, jj, 64);
        hv[u] = xwp[(size_t)sj * 32 + c];
      }
#pragma unroll
      for (int u = 0; u < 8; u++) {
        float2 fv = __half22float2(hv[u]);
        accx = fmaf(pj[u], fv.x, accx);
        accy = fmaf(pj[u], fv.y, accy);
      }
    }
  }
  accx += __shfl_xor(accx, 32, 64);
  accy += __shfl_xor(accy, 32, 64);
  if (lane < 32) {
    float inv = 1.f / (den + 1e-16f);
    float2 b = *(const float2*)(bias + 2 * c);
    float vx = accx * inv + b.x;
    float vy = accy * inv + b.y;
    *(__half2*)(out + (size_t)gw * 64 + 2 * c) = __floats2half2_rn(vx, vy);
  }
}

// ---------------- prediction head: 16 rows/block, LDS weight reuse ----------------
__global__ __launch_bounds__(256) void k_head(const float* __restrict__ uemb,
    const int* __restrict__ uids, const int* __restrict__ iids,
    const __half* __restrict__ x2, const float* __restrict__ pw1,
    const float* __restrict__ pb1, const float* __restrict__ pw2,
    const float* __restrict__ pb2, float* __restrict__ out, int B){
  __shared__ __align__(16) float pw1_s[192 * 64];  // 48KB
  __shared__ float comb_s[16][192];
  for (int i = threadIdx.x; i < 192 * 64 / 4; i += 256)
    ((float4*)pw1_s)[i] = ((const float4*)pw1)[i];
  int w = threadIdx.x >> 6, lane = threadIdx.x & 63;
#pragma unroll
  for (int rr = 0; rr < 4; rr++) {
    int r = w * 4 + rr;
    int b = blockIdx.x * 16 + r;
    if (b < B) {
      int uid = uids[b], iid = iids[b];
      comb_s[r][lane]       = uemb[(size_t)uid * 64 + lane];
      comb_s[r][64 + lane]  = __half2float(x2[(size_t)(NUU + iid) * 64 + lane]);
      comb_s[r][128 + lane] = __half2float(x2[(size_t)uid * 64 + lane]);
    }
  }
  __syncthreads();
  float pw2v = pw2[lane];
  float pb1v = pb1[lane];
#pragma unroll
  for (int rr = 0; rr < 4; rr++) {
    int r = w * 4 + rr;
    int b = blockIdx.x * 16 + r;
    if (b >= B) continue;
    float acc = pb1v;
#pragma unroll 8
    for (int j = 0; j < 192; j++)
      acc = fmaf(comb_s[r][j], pw1_s[j * 64 + lane], acc);
    acc = fmaxf(acc, 0.f);
    float prod = wsum64(acc * pw2v);
    if (lane == 0) out[b] = prod + pb2[0];
  }
}

// ---------------- launcher ----------------
extern "C" void kernel_launch(void* const* d_in, const int* in_sizes, int n_in,
                              void* d_out, int out_size, void* d_ws, size_t ws_size,
                              hipStream_t stream) {
  (void)in_sizes; (void)n_in; (void)out_size; (void)ws_size;
  const int*   user_ids = (const int*)  d_in[0];
  const int*   item_ids = (const int*)  d_in[1];
  const float* content  = (const float*)d_in[2];
  const int*   edge_idx = (const int*)  d_in[3];
  const float* uemb     = (const float*)d_in[4];
  const float* iemb     = (const float*)d_in[5];
  const float* cp_w     = (const float*)d_in[6];
  const float* cp_b     = (const float*)d_in[7];
  const float* w1       = (const float*)d_in[8];
  const float* asrc1    = (const float*)d_in[9];
  const float* adst1    = (const float*)d_in[10];
  const float* b1       = (const float*)d_in[11];
  const float* w2       = (const float*)d_in[12];
  const float* asrc2    = (const float*)d_in[13];
  const float* adst2    = (const float*)d_in[14];
  const float* b2       = (const float*)d_in[15];
  const float* pw1      = (const float*)d_in[16];
  const float* pb1      = (const float*)d_in[17];
  const float* pw2      = (const float*)d_in[18];
  const float* pb2      = (const float*)d_in[19];
  float* out = (float*)d_out;

  // workspace layout (~92 MB)
  __half* x    = (__half*)d_ws;                        // [ND,128] f16; reused as x1
  __half* xw   = x + (size_t)ND * 128;                 // [ND,128] f16 xw1; L2: xw2 + out2
  float* als1  = (float*)(xw + (size_t)ND * 128);      // [ND,2]
  float* ald1  = als1 + (size_t)ND * 2;                // [ND,2]
  float* als2  = ald1 + (size_t)ND * 2;                // [ND]
  float* ald2  = als2 + ND;                            // [ND]
  int* deg     = (int*)(ald2 + ND);                    // [ND]
  int* offs    = deg + ND;                             // [ND+4]
  int* cursor  = offs + ND + 4;                        // [ND]
  int* bsums   = cursor + ND;                          // [160]
  int* csr     = bsums + 160;                          // [ETOT]
  __half* Wt1  = (__half*)(csr + ETOT);                // [128,128]
  __half* Wt2  = Wt1 + 16384;                          // [64,128]
  float* wa1s  = (float*)(Wt2 + 8192);                 // [128,2]
  float* wa1d  = wa1s + 256;                           // [128,2]
  float* wa2s  = wa1d + 256;                           // [128]
  float* wa2d  = wa2s + 128;                           // [128]
  __half* xw2  = xw;                                   // [ND,64]
  __half* out2 = xw + (size_t)ND * 64;                 // [ND,64]

  hipMemsetAsync(x, 0, (size_t)ND * 128 * sizeof(__half), stream);
  hipMemsetAsync(als1, 0, (size_t)ND * 4 * sizeof(float), stream);  // als1+ald1
  hipMemsetAsync(deg, 0, ND * sizeof(int), stream);

  k_conv<<<96, 256, 0, stream>>>(w1, w2, Wt1, Wt2);
  k_wa<<<1, 128, 0, stream>>>(w1, asrc1, adst1, w2, asrc2, adst2, wa1s, wa1d, wa2s, wa2d);

  k_users<<<BB * 64 / 256, 256, 0, stream>>>(user_ids, uemb, x, wa1s, wa1d, als1, ald1);
  k_items<<<BB / 16, 256, 0, stream>>>(content, cp_w, cp_b, iemb, item_ids, x,
                                       wa1s, wa1d, als1, ald1);

  k_count<<<(ETOT + 255) / 256, 256, 0, stream>>>(edge_idx, deg);
  k_scan1<<<NBLK_SCAN, 256, 0, stream>>>(deg, bsums, ND);
  k_scan2<<<1, 64, 0, stream>>>(bsums, NBLK_SCAN, offs + ND);
  k_scan3<<<NBLK_SCAN, 256, 0, stream>>>(deg, bsums, offs, cursor, ND);
  k_fill<<<(ETOT + 255) / 256, 256, 0, stream>>>(edge_idx, cursor, csr);

  // ----- GAT layer 1 (H=2) -----
  k_mfma<8><<<(ND + 127) / 128, 256, 0, stream>>>(x, Wt1, xw, ND);
  k_agg2<<<(ND * 64 + 255) / 256, 256, 0, stream>>>(xw, als1, ald1, offs, csr, b1, x,
                                                    wa2s, wa2d, als2, ald2, ND);

  // ----- GAT layer 2 (H=1) -----
  k_mfma<4><<<(ND + 127) / 128, 256, 0, stream>>>(x, Wt2, xw2, ND);
  k_agg1<<<(ND * 64 + 255) / 256, 256, 0, stream>>>(xw2, als2, ald2, offs, csr, b2, out2, ND);

  // ----- head -----
  k_head<<<(BB + 15) / 16, 256, 0, stream>>>(uemb, user_ids, item_ids, out2,
                                             pw1, pb1, pw2, pb2, out, BB);
}

// Round 4
// 544.114 us; speedup vs baseline: 1.8322x; 1.2602x over previous
//
#include <hip/hip_runtime.h>
#include <hip/hip_fp16.h>
#include <math.h>

// Problem constants (match reference)
static constexpr int ND  = 150000;   // total nodes
static constexpr int NUU = 100000;   // num users
static constexpr int BB  = 16384;    // batch
static constexpr int EE  = 2000000;  // edges (before self loops)
static constexpr int ETOT = EE + ND; // edges incl self loops

// bucket sort params
static constexpr int NBUK  = (ND + 127) >> 7;          // 1172 buckets of 128 nodes
static constexpr int CAP   = 4096;                     // per-bucket capacity (avg ~1835, 55 sigma)
static constexpr int CHUNK = 8192;
static constexpr int NCH   = (ETOT + CHUNK - 1) / CHUNK;

typedef _Float16 h8 __attribute__((ext_vector_type(8)));
typedef float    f4 __attribute__((ext_vector_type(4)));

// ---------------- wave helpers ----------------
__device__ __forceinline__ float wsum64(float v){
#pragma unroll
  for (int d = 32; d > 0; d >>= 1) v += __shfl_xor(v, d, 64);
  return v;
}

// ---------------- weight prep ----------------
__global__ __launch_bounds__(256) void k_conv(const float* __restrict__ w1,
    const float* __restrict__ w2, __half* __restrict__ Wt1, __half* __restrict__ Wt2){
  int t = blockIdx.x * 256 + threadIdx.x;
  if (t < 16384) {
    int n = t >> 7, k = t & 127;
    Wt1[t] = __float2half(w1[k * 128 + n]);
  } else if (t < 24576) {
    int u = t - 16384;
    int n = u >> 7, k = u & 127;
    Wt2[u] = __float2half(w2[k * 64 + n]);
  }
}

// wa = W @ a^T
__global__ __launch_bounds__(128) void k_wa(const float* __restrict__ w1,
    const float* __restrict__ asrc1, const float* __restrict__ adst1,
    const float* __restrict__ w2, const float* __restrict__ asrc2,
    const float* __restrict__ adst2,
    float* __restrict__ wa1s, float* __restrict__ wa1d,
    float* __restrict__ wa2s, float* __restrict__ wa2d){
  int k = threadIdx.x;  // 0..127
  float s0 = 0.f, s1 = 0.f, d0 = 0.f, d1 = 0.f, s2 = 0.f, d2 = 0.f;
  for (int c = 0; c < 64; c++) {
    float wA = w1[k * 128 + c];
    float wB = w1[k * 128 + 64 + c];
    s0 = fmaf(wA, asrc1[c], s0);       d0 = fmaf(wA, adst1[c], d0);
    s1 = fmaf(wB, asrc1[64 + c], s1);  d1 = fmaf(wB, adst1[64 + c], d1);
    float wC = w2[k * 64 + c];
    s2 = fmaf(wC, asrc2[c], s2);       d2 = fmaf(wC, adst2[c], d2);
  }
  wa1s[k * 2] = s0; wa1s[k * 2 + 1] = s1;
  wa1d[k * 2] = d0; wa1d[k * 2 + 1] = d1;
  wa2s[k] = s2; wa2d[k] = d2;
}

// ---------------- input scatter (fp16 x) + fused layer-1 scores ----------------
__global__ __launch_bounds__(256) void k_users(const int* __restrict__ uids,
    const float* __restrict__ uemb, __half* __restrict__ x,
    const float* __restrict__ wa1s, const float* __restrict__ wa1d,
    float* __restrict__ als1, float* __restrict__ ald1){
  int t = blockIdx.x * 256 + threadIdx.x;
  int b = t >> 6, c = t & 63;          // one wave per row
  int uid = uids[b];
  float u = uemb[(size_t)uid * 64 + c];
  x[(size_t)uid * 128 + c] = __float2half(u);
  float2 ws = *(const float2*)(wa1s + 2 * c);
  float2 wd = *(const float2*)(wa1d + 2 * c);
  float s0 = wsum64(u * ws.x);
  float s1 = wsum64(u * ws.y);
  float d0 = wsum64(u * wd.x);
  float d1 = wsum64(u * wd.y);
  if (c == 0) {
    *(float2*)(als1 + (size_t)uid * 2) = make_float2(s0, s1);
    *(float2*)(ald1 + (size_t)uid * 2) = make_float2(d0, d1);
  }
}

__global__ __launch_bounds__(256) void k_items(const float* __restrict__ content,
    const float* __restrict__ cpw, const float* __restrict__ cpb,
    const float* __restrict__ iemb, const int* __restrict__ iids,
    __half* __restrict__ x,
    const float* __restrict__ wa1s, const float* __restrict__ wa1d,
    float* __restrict__ als1, float* __restrict__ ald1){
  int c  = threadIdx.x & 63;
  int rr = threadIdx.x >> 6;
  int r0 = blockIdx.x * 16 + rr * 4;
  float acc[4] = {0.f, 0.f, 0.f, 0.f};
  for (int k = 0; k < 256; k++) {
    float wv = cpw[k * 64 + c];
#pragma unroll
    for (int i = 0; i < 4; i++)
      acc[i] = fmaf(content[(size_t)(r0 + i) * 256 + k], wv, acc[i]);
  }
  float2 wsL = *(const float2*)(wa1s + 2 * c);
  float2 wdL = *(const float2*)(wa1d + 2 * c);
  float2 wsH = *(const float2*)(wa1s + 128 + 2 * c);
  float2 wdH = *(const float2*)(wa1d + 128 + 2 * c);
#pragma unroll
  for (int i = 0; i < 4; i++) {
    int r = r0 + i;
    if (r >= BB) continue;
    int iid = iids[r];
    size_t node = (size_t)(NUU + iid);
    float hi = acc[i] + cpb[c];
    float lo = iemb[(size_t)iid * 64 + c];
    x[node * 128 + 64 + c] = __float2half(hi);
    x[node * 128 + c]      = __float2half(lo);
    float s0 = wsum64(lo * wsL.x + hi * wsH.x);
    float s1 = wsum64(lo * wsL.y + hi * wsH.y);
    float d0 = wsum64(lo * wdL.x + hi * wdH.x);
    float d1 = wsum64(lo * wdL.y + hi * wdH.y);
    if (c == 0) {
      *(float2*)(als1 + node * 2) = make_float2(s0, s1);
      *(float2*)(ald1 + node * 2) = make_float2(d0, d1);
    }
  }
}

// ---------------- CSR build via bucket sort ----------------
// pass 1: bin edges into NBUK buckets (bucket = dst>>7). One device atomic per
// (block,bucket); per-block ranks are contiguous so writes are ~line-sized.
__global__ __launch_bounds__(256) void k_bin(const int* __restrict__ ei,
    int* __restrict__ bucket_cnt, int2* __restrict__ bucket_data){
  __shared__ int hist[NBUK];
  __shared__ int base[NBUK];
  int tid = threadIdx.x;
  int t0 = blockIdx.x * CHUNK;
  for (int i = tid; i < NBUK; i += 256) hist[i] = 0;
  __syncthreads();
  for (int i = tid; i < CHUNK; i += 256) {
    int t = t0 + i;
    if (t >= ETOT) break;
    int dst = (t < EE) ? ei[EE + t] : (t - EE);
    atomicAdd(&hist[dst >> 7], 1);
  }
  __syncthreads();
  for (int b = tid; b < NBUK; b += 256) {
    int c = hist[b];
    base[b] = c ? atomicAdd(&bucket_cnt[b], c) : 0;
    hist[b] = 0;
  }
  __syncthreads();
  for (int i = tid; i < CHUNK; i += 256) {
    int t = t0 + i;
    if (t >= ETOT) break;
    int src, dst;
    if (t < EE) { src = ei[t]; dst = ei[EE + t]; }
    else        { src = dst = t - EE; }
    int b = dst >> 7;
    int r = base[b] + atomicAdd(&hist[b], 1);
    if (r < CAP) bucket_data[(size_t)b * CAP + r] = make_int2(src, dst);
  }
}

// pass 2: exclusive scan of bucket counts (1 wave)
__global__ void k_bscan(const int* __restrict__ cnt, int* __restrict__ bbase,
                        int* __restrict__ offs_end){
  int lane = threadIdx.x;   // 64 threads
  int carry = 0;
  for (int c0 = 0; c0 < NBUK; c0 += 64) {
    int i = c0 + lane;
    int v = (i < NBUK) ? cnt[i] : 0;
    int x = v;
#pragma unroll
    for (int d = 1; d < 64; d <<= 1) { int t = __shfl_up(x, d, 64); if (lane >= d) x += t; }
    if (i < NBUK) bbase[i] = carry + x - v;
    carry += __shfl(x, 63, 64);
  }
  if (lane == 0) *offs_end = carry;   // offs[ND] = ETOT
}

// pass 3: per-bucket deg count + in-block scan -> offs (coalesced), then
// scatter csr within the bucket's ~30 KB window (L2-resident).
__global__ __launch_bounds__(256) void k_bucket(const int2* __restrict__ bucket_data,
    const int* __restrict__ bucket_cnt, const int* __restrict__ bbase,
    int* __restrict__ offs, int* __restrict__ csr){
  __shared__ int degL[128];
  __shared__ int curL[128];
  int b = blockIdx.x;
  int tid = threadIdx.x;
  int cnt = bucket_cnt[b];
  int base = bbase[b];
  if (tid < 128) degL[tid] = 0;
  __syncthreads();
  const int2* bd = bucket_data + (size_t)b * CAP;
  for (int i = tid; i < cnt; i += 256)
    atomicAdd(&degL[bd[i].y & 127], 1);
  __syncthreads();
  if (tid < 64) {   // wave 0: exclusive scan of 128 degs
    int v0 = degL[tid], v1 = degL[64 + tid];
    int s0 = v0, s1 = v1;
#pragma unroll
    for (int d = 1; d < 64; d <<= 1) {
      int t0 = __shfl_up(s0, d, 64); if (tid >= d) s0 += t0;
      int t1 = __shfl_up(s1, d, 64); if (tid >= d) s1 += t1;
    }
    int tot0 = __shfl(s0, 63, 64);
    int e0 = s0 - v0;
    int e1 = s1 - v1 + tot0;
    curL[tid] = e0; curL[64 + tid] = e1;
    int g0 = b * 128 + tid, g1 = b * 128 + 64 + tid;
    if (g0 < ND) offs[g0] = base + e0;
    if (g1 < ND) offs[g1] = base + e1;
  }
  __syncthreads();
  for (int i = tid; i < cnt; i += 256) {
    int2 e = bd[i];
    int p = atomicAdd(&curL[e.y & 127], 1);
    csr[base + p] = e.x;
  }
}

// ---------------- MFMA fp16 GEMM: C[M,N](f16) = A[M,128](f16) @ Bt[N,128]^T ----------------
template<int NT>   // N = NT*16
__global__ __launch_bounds__(256) void k_mfma(const __half* __restrict__ A,
    const __half* __restrict__ Bt, __half* __restrict__ C, int M){
  constexpr int N = NT * 16;
  int wid  = (blockIdx.x * 256 + threadIdx.x) >> 6;
  int lane = threadIdx.x & 63;
  int q = lane >> 4, mr = lane & 15;
  int r0 = wid * 32;
  if (r0 >= M) return;
  int row0 = min(r0 + mr, M - 1);
  int row1 = min(r0 + 16 + mr, M - 1);
  f4 acc[2][NT];
#pragma unroll
  for (int i = 0; i < 2; i++)
#pragma unroll
    for (int j = 0; j < NT; j++) acc[i][j] = (f4)0.f;
#pragma unroll
  for (int ks = 0; ks < 4; ks++) {
    int ko = ks * 32 + q * 8;
    h8 a0 = *(const h8*)(A + (size_t)row0 * 128 + ko);
    h8 a1 = *(const h8*)(A + (size_t)row1 * 128 + ko);
#pragma unroll
    for (int nt = 0; nt < NT; nt++) {
      h8 b = *(const h8*)(Bt + (size_t)(nt * 16 + mr) * 128 + ko);
      acc[0][nt] = __builtin_amdgcn_mfma_f32_16x16x32_f16(a0, b, acc[0][nt], 0, 0, 0);
      acc[1][nt] = __builtin_amdgcn_mfma_f32_16x16x32_f16(a1, b, acc[1][nt], 0, 0, 0);
    }
  }
#pragma unroll
  for (int mt = 0; mt < 2; mt++)
#pragma unroll
    for (int r = 0; r < 4; r++) {
      int row = r0 + mt * 16 + q * 4 + r;
      if (row < M) {
#pragma unroll
        for (int nt = 0; nt < NT; nt++)
          C[(size_t)row * N + nt * 16 + mr] = __float2half(acc[mt][nt][r]);
      }
    }
}

// ---------------- GAT aggregation, H=2 (layer 1) ----------------
__global__ __launch_bounds__(256) void k_agg2(const __half* __restrict__ xw,
    const float* __restrict__ als, const float* __restrict__ ald,
    const int* __restrict__ offs, const int* __restrict__ csr,
    const float* __restrict__ bias, __half* __restrict__ out,
    const float* __restrict__ wa2s, const float* __restrict__ wa2d,
    float* __restrict__ als2, float* __restrict__ ald2, int n){
  int gw = (blockIdx.x * 256 + threadIdx.x) >> 6;
  int lane = threadIdx.x & 63;
  if (gw >= n) return;
  int e0 = offs[gw], e1 = offs[gw + 1];
  float2 aldv = *(const float2*)(ald + (size_t)gw * 2);
  bool lo = lane < 32;
  float den0 = 0.f, den1 = 0.f, accx = 0.f, accy = 0.f;
  const __half2* xwp = (const __half2*)xw;
  for (int base = e0; base < e1; base += 64) {
    int e = base + lane;
    bool valid = (e < e1);
    int src = valid ? csr[e] : 0;
    float p0 = 0.f, p1 = 0.f;
    if (valid) {
      float2 a = *(const float2*)(als + (size_t)src * 2);
      float v0 = a.x + aldv.x, v1 = a.y + aldv.y;
      v0 = (v0 > 0.f) ? v0 : 0.2f * v0;
      v1 = (v1 > 0.f) ? v1 : 0.2f * v1;
      p0 = __expf(v0); p1 = __expf(v1);
    }
    den0 += wsum64(p0);
    den1 += wsum64(p1);
    int cnt = min(e1 - base, 64);
    for (int j0 = 0; j0 < cnt; j0 += 8) {
      __half2 hv[8]; float pj[8];
#pragma unroll
      for (int u = 0; u < 8; u++) {
        int jj = j0 + u;
        int sj = __shfl(src, jj, 64);
        float q0 = __shfl(p0, jj, 64);
        float q1 = __shfl(p1, jj, 64);
        pj[u] = lo ? q0 : q1;
        hv[u] = xwp[(size_t)sj * 64 + lane];
      }
#pragma unroll
      for (int u = 0; u < 8; u++) {
        float2 fv = __half22float2(hv[u]);
        accx = fmaf(pj[u], fv.x, accx);
        accy = fmaf(pj[u], fv.y, accy);
      }
    }
  }
  float den = (lo ? den0 : den1) + 1e-16f;
  float inv = 1.f / den;
  float2 b = *(const float2*)(bias + 2 * lane);
  float vx = accx * inv + b.x;
  float vy = accy * inv + b.y;
  vx = (vx > 0.f) ? vx : expm1f(vx);             // elu
  vy = (vy > 0.f) ? vy : expm1f(vy);
  *(__half2*)(out + (size_t)gw * 128 + 2 * lane) = __floats2half2_rn(vx, vy);
  float2 ws = *(const float2*)(wa2s + 2 * lane);
  float2 wd = *(const float2*)(wa2d + 2 * lane);
  float s_s = wsum64(vx * ws.x + vy * ws.y);
  float s_d = wsum64(vx * wd.x + vy * wd.y);
  if (lane == 0) { als2[gw] = s_s; ald2[gw] = s_d; }
}

// ---------------- GAT aggregation, H=1 (layer 2): 2 edges per instruction ----------------
__global__ __launch_bounds__(256) void k_agg1(const __half* __restrict__ xw,
    const float* __restrict__ als, const float* __restrict__ ald,
    const int* __restrict__ offs, const int* __restrict__ csr,
    const float* __restrict__ bias, __half* __restrict__ out, int n){
  int gw = (blockIdx.x * 256 + threadIdx.x) >> 6;
  int lane = threadIdx.x & 63;
  if (gw >= n) return;
  int e0 = offs[gw], e1 = offs[gw + 1];
  float aldd = ald[gw];
  float den = 0.f, accx = 0.f, accy = 0.f;
  int hid = lane >> 5;
  int c = lane & 31;
  const __half2* xwp = (const __half2*)xw;
  for (int base = e0; base < e1; base += 64) {
    int e = base + lane;
    bool valid = (e < e1);
    int src = valid ? csr[e] : 0;
    float p = 0.f;
    if (valid) {
      float v = als[src] + aldd;
      v = (v > 0.f) ? v : 0.2f * v;
      p = __expf(v);
    }
    den += wsum64(p);
    int cnt = min(e1 - base, 64);
    for (int j0 = 0; j0 < cnt; j0 += 16) {
      __half2 hv[8]; float pj[8];
#pragma unroll
      for (int u = 0; u < 8; u++) {
        int jj = j0 + 2 * u + hid;
        int sj = __shfl(src, jj, 64);
        pj[u] = __shfl(p, jj, 64);
        hv[u] = xwp[(size_t)sj * 32 + c];
      }
#pragma unroll
      for (int u = 0; u < 8; u++) {
        float2 fv = __half22float2(hv[u]);
        accx = fmaf(pj[u], fv.x, accx);
        accy = fmaf(pj[u], fv.y, accy);
      }
    }
  }
  accx += __shfl_xor(accx, 32, 64);
  accy += __shfl_xor(accy, 32, 64);
  if (lane < 32) {
    float inv = 1.f / (den + 1e-16f);
    float2 b = *(const float2*)(bias + 2 * c);
    float vx = accx * inv + b.x;
    float vy = accy * inv + b.y;
    *(__half2*)(out + (size_t)gw * 64 + 2 * c) = __floats2half2_rn(vx, vy);
  }
}

// ---------------- prediction head: 16 rows/block, LDS weight reuse ----------------
__global__ __launch_bounds__(256) void k_head(const float* __restrict__ uemb,
    const int* __restrict__ uids, const int* __restrict__ iids,
    const __half* __restrict__ x2, const float* __restrict__ pw1,
    const float* __restrict__ pb1, const float* __restrict__ pw2,
    const float* __restrict__ pb2, float* __restrict__ out, int B){
  __shared__ __align__(16) float pw1_s[192 * 64];  // 48KB
  __shared__ float comb_s[16][192];
  for (int i = threadIdx.x; i < 192 * 64 / 4; i += 256)
    ((float4*)pw1_s)[i] = ((const float4*)pw1)[i];
  int w = threadIdx.x >> 6, lane = threadIdx.x & 63;
#pragma unroll
  for (int rr = 0; rr < 4; rr++) {
    int r = w * 4 + rr;
    int b = blockIdx.x * 16 + r;
    if (b < B) {
      int uid = uids[b], iid = iids[b];
      comb_s[r][lane]       = uemb[(size_t)uid * 64 + lane];
      comb_s[r][64 + lane]  = __half2float(x2[(size_t)(NUU + iid) * 64 + lane]);
      comb_s[r][128 + lane] = __half2float(x2[(size_t)uid * 64 + lane]);
    }
  }
  __syncthreads();
  float pw2v = pw2[lane];
  float pb1v = pb1[lane];
#pragma unroll
  for (int rr = 0; rr < 4; rr++) {
    int r = w * 4 + rr;
    int b = blockIdx.x * 16 + r;
    if (b >= B) continue;
    float acc = pb1v;
#pragma unroll 8
    for (int j = 0; j < 192; j++)
      acc = fmaf(comb_s[r][j], pw1_s[j * 64 + lane], acc);
    acc = fmaxf(acc, 0.f);
    float prod = wsum64(acc * pw2v);
    if (lane == 0) out[b] = prod + pb2[0];
  }
}

// ---------------- launcher ----------------
extern "C" void kernel_launch(void* const* d_in, const int* in_sizes, int n_in,
                              void* d_out, int out_size, void* d_ws, size_t ws_size,
                              hipStream_t stream) {
  (void)in_sizes; (void)n_in; (void)out_size; (void)ws_size;
  const int*   user_ids = (const int*)  d_in[0];
  const int*   item_ids = (const int*)  d_in[1];
  const float* content  = (const float*)d_in[2];
  const int*   edge_idx = (const int*)  d_in[3];
  const float* uemb     = (const float*)d_in[4];
  const float* iemb     = (const float*)d_in[5];
  const float* cp_w     = (const float*)d_in[6];
  const float* cp_b     = (const float*)d_in[7];
  const float* w1       = (const float*)d_in[8];
  const float* asrc1    = (const float*)d_in[9];
  const float* adst1    = (const float*)d_in[10];
  const float* b1       = (const float*)d_in[11];
  const float* w2       = (const float*)d_in[12];
  const float* asrc2    = (const float*)d_in[13];
  const float* adst2    = (const float*)d_in[14];
  const float* b2       = (const float*)d_in[15];
  const float* pw1      = (const float*)d_in[16];
  const float* pb1      = (const float*)d_in[17];
  const float* pw2      = (const float*)d_in[18];
  const float* pb2      = (const float*)d_in[19];
  float* out = (float*)d_out;

  // workspace layout (~128 MB)
  __half* x    = (__half*)d_ws;                        // [ND,128] f16; reused as x1
  __half* xw   = x + (size_t)ND * 128;                 // [ND,128] f16 xw1; L2: xw2 + out2
  float* als1  = (float*)(xw + (size_t)ND * 128);      // [ND,2]
  float* ald1  = als1 + (size_t)ND * 2;                // [ND,2]
  float* als2  = ald1 + (size_t)ND * 2;                // [ND]
  float* ald2  = als2 + ND;                            // [ND]
  int* offs    = (int*)(ald2 + ND);                    // [ND+4]
  int* bcnt    = offs + ND + 4;                        // [NBUK]
  int* bbase   = bcnt + NBUK;                          // [NBUK]
  int* csr     = bbase + NBUK;                         // [ETOT]
  int2* bdata  = (int2*)(csr + ETOT + 2);              // [NBUK*CAP] 8B-aligned
  __half* Wt1  = (__half*)(bdata + (size_t)NBUK * CAP); // [128,128]
  __half* Wt2  = Wt1 + 16384;                          // [64,128]
  float* wa1s  = (float*)(Wt2 + 8192);                 // [128,2]
  float* wa1d  = wa1s + 256;                           // [128,2]
  float* wa2s  = wa1d + 256;                           // [128]
  float* wa2d  = wa2s + 128;                           // [128]
  __half* xw2  = xw;                                   // [ND,64]
  __half* out2 = xw + (size_t)ND * 64;                 // [ND,64]

  hipMemsetAsync(x, 0, (size_t)ND * 128 * sizeof(__half), stream);
  hipMemsetAsync(als1, 0, (size_t)ND * 4 * sizeof(float), stream);  // als1+ald1
  hipMemsetAsync(bcnt, 0, NBUK * sizeof(int), stream);

  k_conv<<<96, 256, 0, stream>>>(w1, w2, Wt1, Wt2);
  k_wa<<<1, 128, 0, stream>>>(w1, asrc1, adst1, w2, asrc2, adst2, wa1s, wa1d, wa2s, wa2d);

  k_users<<<BB * 64 / 256, 256, 0, stream>>>(user_ids, uemb, x, wa1s, wa1d, als1, ald1);
  k_items<<<BB / 16, 256, 0, stream>>>(content, cp_w, cp_b, iemb, item_ids, x,
                                       wa1s, wa1d, als1, ald1);

  // CSR build: bucket sort (no device-atomic scatter, no write amplification)
  k_bin<<<NCH, 256, 0, stream>>>(edge_idx, bcnt, bdata);
  k_bscan<<<1, 64, 0, stream>>>(bcnt, bbase, offs + ND);
  k_bucket<<<NBUK, 256, 0, stream>>>(bdata, bcnt, bbase, offs, csr);

  // ----- GAT layer 1 (H=2) -----
  k_mfma<8><<<(ND + 127) / 128, 256, 0, stream>>>(x, Wt1, xw, ND);
  k_agg2<<<(ND * 64 + 255) / 256, 256, 0, stream>>>(xw, als1, ald1, offs, csr, b1, x,
                                                    wa2s, wa2d, als2, ald2, ND);

  // ----- GAT layer 2 (H=1) -----
  k_mfma<4><<<(ND + 127) / 128, 256, 0, stream>>>(x, Wt2, xw2, ND);
  k_agg1<<<(ND * 64 + 255) / 256, 256, 0, stream>>>(xw2, als2, ald2, offs, csr, b2, out2, ND);

  // ----- head -----
  k_head<<<(BB + 15) / 16, 256, 0, stream>>>(uemb, user_ids, item_ids, out2,
                                             pw1, pb1, pw2, pb2, out, BB);
}